// Round 3
// baseline (45.332 us; speedup 1.0000x reference)
//
#include <hip/hip_runtime.h>

#define MEMN 262144
#define DIM 128
#define BS 256
#define NPOS 8
#define NNEG 1024
#define KTOT (1 + NPOS + NNEG)        /* 1033 */
#define RPB 128                       /* rows per block: 16 groups x 8 */
#define NCHUNK ((KTOT + RPB - 1) / RPB) /* 9 */
#define R 8

__global__ __launch_bounds__(256) void avid_sim_kernel(
    const float* __restrict__ video, const float* __restrict__ audio,
    const float* __restrict__ view1, const float* __restrict__ view2,
    const int* __restrict__ y, const int* __restrict__ pos,
    const int* __restrict__ neg, float* __restrict__ out)
{
    const int bid   = blockIdx.x;
    const int m     = bid / (BS * NCHUNK);      // 0: v2a (q=video, mem=view2); 1: a2v
    const int rem   = bid - m * (BS * NCHUNK);
    const int b     = rem / NCHUNK;
    const int chunk = rem - b * NCHUNK;

    const float* q_src = (m == 0) ? (video + b * DIM) : (audio + b * DIM);
    const float* memt  = (m == 0) ? view2 : view1;

    const int g   = threadIdx.x & 15;   // lane in 16-lane group
    const int grp = threadIdx.x >> 4;   // 16 groups per block

    // ---- per-group index fetch: lane g<8 loads idx for k = base + g*16 ----
    const int kbase = chunk * RPB + grp;
    int idx_g = 0;
    if (g < R) {
        int kk = kbase + g * 16;
        if (kk >= KTOT) kk = KTOT - 1;           // clamp (last chunk only)
        if (kk == 0)          idx_g = y[b];
        else if (kk <= NPOS)  idx_g = pos[b * NPOS + (kk - 1)];
        else                  idx_g = neg[b * NNEG + (kk - 1 - NPOS)];
    }

    // ---- query fragment + fused L2 normalization (group-local, no barrier) ----
    float4 q0 = *(const float4*)(q_src + g * 8);
    float4 q1 = *(const float4*)(q_src + g * 8 + 4);
    float qq = q0.x*q0.x + q0.y*q0.y + q0.z*q0.z + q0.w*q0.w
             + q1.x*q1.x + q1.y*q1.y + q1.z*q1.z + q1.w*q1.w;
    qq += __shfl_xor(qq, 1);
    qq += __shfl_xor(qq, 2);
    qq += __shfl_xor(qq, 4);
    qq += __shfl_xor(qq, 8);
    const float scale = (1.0f / 0.07f) / fmaxf(sqrtf(qq), 1e-12f);
    q0.x *= scale; q0.y *= scale; q0.z *= scale; q0.w *= scale;
    q1.x *= scale; q1.y *= scale; q1.z *= scale; q1.w *= scale;

    // ---- distribute indices within the group, issue all row loads ----
    const float* rowp[R];
#pragma unroll
    for (int i = 0; i < R; ++i) {
        int idx = __shfl(idx_g, i, 16);          // group-sub-partition shuffle
        rowp[i] = memt + (size_t)idx * DIM + g * 8;
    }

    float* outm = out + (size_t)m * BS * KTOT + (size_t)b * KTOT;

    float4 r0[R], r1[R];
#pragma unroll
    for (int i = 0; i < R; ++i) {
        if (kbase + i * 16 < KTOT) {             // group-uniform guard
            r0[i] = *(const float4*)(rowp[i]);
            r1[i] = *(const float4*)(rowp[i] + 4);
        }
    }
#pragma unroll
    for (int i = 0; i < R; ++i) {
        const int k = kbase + i * 16;
        if (k < KTOT) {
            float s = q0.x*r0[i].x + q0.y*r0[i].y + q0.z*r0[i].z + q0.w*r0[i].w
                    + q1.x*r1[i].x + q1.y*r1[i].y + q1.z*r1[i].z + q1.w*r1[i].w;
            s += __shfl_xor(s, 1);
            s += __shfl_xor(s, 2);
            s += __shfl_xor(s, 4);
            s += __shfl_xor(s, 8);
            if (g == 0) outm[k] = s;
        }
    }
}

extern "C" void kernel_launch(void* const* d_in, const int* in_sizes, int n_in,
                              void* d_out, int out_size, void* d_ws, size_t ws_size,
                              hipStream_t stream) {
    const float* video = (const float*)d_in[0];
    const float* audio = (const float*)d_in[1];
    const float* view1 = (const float*)d_in[2];
    const float* view2 = (const float*)d_in[3];
    const int*   y     = (const int*)d_in[4];
    const int*   pos   = (const int*)d_in[5];
    const int*   neg   = (const int*)d_in[6];
    float* out = (float*)d_out;

    dim3 grid(2 * BS * NCHUNK);
    dim3 block(256);
    avid_sim_kernel<<<grid, block, 0, stream>>>(video, audio, view1, view2,
                                                y, pos, neg, out);
}